// Round 7
// baseline (190.126 us; speedup 1.0000x reference)
//
#include <hip/hip_runtime.h>
#include <hip/hip_bf16.h>

#define N_SRCN 200000
#define N_DSTN 50000
#define NEDGE 800000
#define KIN 256
#define NF 192        // H*OUT = 3*64
#define SLOPE 0.2f
#define NRB 3125      // row-blocks of 64

typedef __attribute__((ext_vector_type(8))) short bf16x8;
typedef __attribute__((ext_vector_type(4))) float f32x4;

__device__ __forceinline__ unsigned short f2bf(float f) {
    union { float f; unsigned int u; } v; v.f = f;
    unsigned int u = v.u;
    return (unsigned short)((u + 0x7FFFu + ((u >> 16) & 1u)) >> 16);  // RNE
}
__device__ __forceinline__ float bf2f(unsigned short h) {
    union { unsigned int u; float f; } v; v.u = ((unsigned int)h) << 16;
    return v.f;
}
__device__ __forceinline__ unsigned int cvt2(float lo, float hi) {
    __hip_bfloat162 h = __float22bfloat162_rn(float2{lo, hi});
    union { __hip_bfloat162 h; unsigned int u; } c; c.h = h;
    return c.u;
}

// ---------------- merged prep: blocks 0-23 pack W; blocks 24+ build row_ptr --
// Wp[((ks*12 + nt)*64 + lane)*8 + j] = bf16(W[nt*16 + (lane&15)][ks*32 + (lane>>4)*8 + j])
__global__ void prep_kernel(const float* __restrict__ W, unsigned short* __restrict__ Wp,
                            const int* __restrict__ dst, int* __restrict__ rp) {
    const int bid = blockIdx.x;
    if (bid < 24) {
        int tid = bid * 256 + threadIdx.x;
        if (tid >= 12 * 8 * 64) return;
        int lane = tid & 63;
        int g = tid >> 6;
        int nt = g % 12, ks = g / 12;
        int col = nt * 16 + (lane & 15);
        int k = ks * 32 + (lane >> 4) * 8;
        const float* wsrc = &W[col * KIN + k];
        unsigned short* o = &Wp[tid * 8];
        #pragma unroll
        for (int j = 0; j < 8; ++j) o[j] = f2bf(wsrc[j]);
    } else {
        int d = (bid - 24) * 256 + threadIdx.x;
        if (d > N_DSTN) return;
        int lo = 0, hi = NEDGE;
        while (lo < hi) {
            int mid = (lo + hi) >> 1;
            if (dst[mid] < d) lo = mid + 1; else hi = mid;
        }
        rp[d] = lo;
    }
}

// ---------------- GEMM: feat = x @ W^T (bf16 MFMA) + fused el/er -------------
// One-shot blocks (grid 3125, 4 waves): B in regs once (24 frags, 96 VGPR),
// A reg-staged f32->bf16 into 32KB XOR-swizzled LDS (coalesced), ONE barrier,
// then pure {ds_read_b128 + MFMA} loop — zero global loads on MFMA path.
__launch_bounds__(256)
__global__ void gemm_feat(const float* __restrict__ x, const unsigned short* __restrict__ Wp,
                          const float* __restrict__ attn_l, const float* __restrict__ attn_r,
                          unsigned short* __restrict__ feat,
                          float* __restrict__ el4, float* __restrict__ er4) {
    __shared__ unsigned short Ab[64][256];   // 32 KB bf16, granule-swizzled
    __shared__ float parts[64][4][4][2];     // 8 KB [row][head(pad4)][ntq][l/r]
    const int t = threadIdx.x;
    const int wid = t >> 6, lane = t & 63;
    const int al = lane & 15, ah = lane >> 4;
    const int r0 = blockIdx.x * 64;

    // ---- B preload (once): wave w -> nt = 3w+j (24 x 16B/lane) ----
    bf16x8 bv[8][3];
    #pragma unroll
    for (int ks = 0; ks < 8; ++ks)
        #pragma unroll
        for (int j = 0; j < 3; ++j)
            bv[ks][j] = *(const bf16x8*)&Wp[(size_t)(ks * 12 + wid * 3 + j) * 512 + lane * 8];

    float Al[3], Ar[3];
    #pragma unroll
    for (int j = 0; j < 3; ++j) {
        Al[j] = attn_l[(wid * 3 + j) * 16 + al];
        Ar[j] = attn_r[(wid * 3 + j) * 16 + al];
    }

    // ---- stage A: thread t handles granules G = t + k*256 (G=row*32+g,
    // granule = 8 floats -> bf16x8). Perfectly coalesced loads; LDS granule
    // swizzle g' = g ^ (row&7) (both sides; structural-floor conflicts only).
    {
        float4 va[16];
        #pragma unroll
        for (int k = 0; k < 8; ++k) {
            const int G = t + k * 256;
            const int row = G >> 5, g = G & 31;
            const float* gp = &x[(size_t)(r0 + row) * KIN + g * 8];
            va[2 * k]     = *(const float4*)gp;
            va[2 * k + 1] = *(const float4*)(gp + 4);
        }
        #pragma unroll
        for (int k = 0; k < 8; ++k) {
            const int G = t + k * 256;
            const int row = G >> 5, g = G & 31;
            union { bf16x8 v; unsigned int u[4]; } s;
            s.u[0] = cvt2(va[2 * k].x,     va[2 * k].y);
            s.u[1] = cvt2(va[2 * k].z,     va[2 * k].w);
            s.u[2] = cvt2(va[2 * k + 1].x, va[2 * k + 1].y);
            s.u[3] = cvt2(va[2 * k + 1].z, va[2 * k + 1].w);
            *(bf16x8*)&Ab[row][(g ^ (row & 7)) * 8] = s.v;
        }
    }
    __syncthreads();

    // ---- compute: pure LDS + MFMA (4 rt x 8 ks x 3 nt) ----
    f32x4 acc[4][3] = {};
    #pragma unroll
    for (int ks = 0; ks < 8; ++ks) {
        #pragma unroll
        for (int rt = 0; rt < 4; ++rt) {
            const int row = rt * 16 + al;
            const int g = ks * 4 + ah;               // logical granule
            bf16x8 av = *(const bf16x8*)&Ab[row][(g ^ (row & 7)) * 8];
            #pragma unroll
            for (int j = 0; j < 3; ++j)
                acc[rt][j] = __builtin_amdgcn_mfma_f32_16x16x32_bf16(av, bv[ks][j], acc[rt][j], 0, 0, 0);
        }
    }

    // ---- epilogue 1: feat store (C/D: col=nt*16+al, row=ah*4+e [m89]) ----
    #pragma unroll
    for (int rt = 0; rt < 4; ++rt)
        #pragma unroll
        for (int j = 0; j < 3; ++j) {
            const int col = (wid * 3 + j) * 16 + al;
            #pragma unroll
            for (int e = 0; e < 4; ++e) {
                const int row = r0 + rt * 16 + ah * 4 + e;
                feat[(size_t)row * NF + col] = f2bf(acc[rt][j][e]);
            }
        }

    // ---- epilogue 2: el/er partials (16-lane reduce per nt) ----
    #pragma unroll
    for (int rt = 0; rt < 4; ++rt)
        #pragma unroll
        for (int e = 0; e < 4; ++e)
            #pragma unroll
            for (int j = 0; j < 3; ++j) {
                float sl = acc[rt][j][e] * Al[j];
                float sr = acc[rt][j][e] * Ar[j];
                #pragma unroll
                for (int m = 1; m <= 8; m <<= 1) {
                    sl += __shfl_xor(sl, m);
                    sr += __shfl_xor(sr, m);
                }
                if (al == 0) {
                    const int rloc = rt * 16 + ah * 4 + e;
                    const int nt = wid * 3 + j;
                    parts[rloc][nt >> 2][nt & 3][0] = sl;
                    parts[rloc][nt >> 2][nt & 3][1] = sr;
                }
            }
    __syncthreads();

    // ---- reduce parts -> el4/er4 (row = t>>2, h = t&3; h==3 pads) ----
    {
        const int rloc = t >> 2, h = t & 3;
        const int row = r0 + rloc;
        float sl = 0.f, sr = 0.f;
        if (h < 3) {
            sl = parts[rloc][h][0][0] + parts[rloc][h][1][0]
               + parts[rloc][h][2][0] + parts[rloc][h][3][0];
            sr = parts[rloc][h][0][1] + parts[rloc][h][1][1]
               + parts[rloc][h][2][1] + parts[rloc][h][3][1];
        }
        el4[(size_t)row * 4 + h] = sl;
        if (row < N_DSTN) er4[(size_t)row * 4 + h] = sr;
    }
}

// ---------------- gather: edge softmax (no max shift) + weighted accumulate --
__launch_bounds__(256)
__global__ void gather_kernel(const unsigned short* __restrict__ feat,
                              const float* __restrict__ el4, const float* __restrict__ er4,
                              const int* __restrict__ src, const int* __restrict__ rp,
                              float* __restrict__ out) {
    const int lane = threadIdx.x & 63;
    const int d = (blockIdx.x * blockDim.x + threadIdx.x) >> 6;
    if (d >= N_DSTN) return;
    const int lo = rp[d], hi = rp[d + 1];
    const float4 erv = *(const float4*)&er4[(size_t)d * 4];

    float a0 = 0.f, a1 = 0.f, a2 = 0.f, s0 = 0.f, s1 = 0.f, s2 = 0.f;
    for (int base = lo; base < hi; base += 64) {
        const int cnt = min(64, hi - base);
        int sv = 0; float w0 = 0.f, w1 = 0.f, w2 = 0.f;
        if (lane < cnt) {
            sv = src[base + lane];
            const float4 elv = *(const float4*)&el4[(size_t)sv * 4];
            float e0 = elv.x + erv.x; e0 = e0 >= 0.f ? e0 : SLOPE * e0; w0 = __expf(e0);
            float e1 = elv.y + erv.y; e1 = e1 >= 0.f ? e1 : SLOPE * e1; w1 = __expf(e1);
            float e2 = elv.z + erv.z; e2 = e2 >= 0.f ? e2 : SLOPE * e2; w2 = __expf(e2);
        }
        int j = 0;
        for (; j + 8 <= cnt; j += 8) {
            unsigned short f0[8], f1[8], f2[8];
            float u0[8], u1[8], u2[8];
            #pragma unroll
            for (int q = 0; q < 8; ++q) {
                const int sj = __shfl(sv, j + q);
                const unsigned short* fp = &feat[(size_t)sj * NF + lane];
                f0[q] = fp[0]; f1[q] = fp[64]; f2[q] = fp[128];
                u0[q] = __shfl(w0, j + q);
                u1[q] = __shfl(w1, j + q);
                u2[q] = __shfl(w2, j + q);
            }
            #pragma unroll
            for (int q = 0; q < 8; ++q) {
                s0 += u0[q]; a0 += u0[q] * bf2f(f0[q]);
                s1 += u1[q]; a1 += u1[q] * bf2f(f1[q]);
                s2 += u2[q]; a2 += u2[q] * bf2f(f2[q]);
            }
        }
        for (; j < cnt; ++j) {
            const int sj = __shfl(sv, j);
            const float u0 = __shfl(w0, j);
            const float u1 = __shfl(w1, j);
            const float u2 = __shfl(w2, j);
            const unsigned short* fp = &feat[(size_t)sj * NF + lane];
            s0 += u0; a0 += u0 * bf2f(fp[0]);
            s1 += u1; a1 += u1 * bf2f(fp[64]);
            s2 += u2; a2 += u2 * bf2f(fp[128]);
        }
    }
    if (hi == lo) { s0 = 1.f; s1 = 1.f; s2 = 1.f; }
    float* op = &out[(size_t)d * NF];
    op[lane]       = a0 / s0;
    op[64 + lane]  = a1 / s1;
    op[128 + lane] = a2 / s2;
}

extern "C" void kernel_launch(void* const* d_in, const int* in_sizes, int n_in,
                              void* d_out, int out_size, void* d_ws, size_t ws_size,
                              hipStream_t stream) {
    const float* x      = (const float*)d_in[0];
    const float* W      = (const float*)d_in[1];
    const float* attn_l = (const float*)d_in[2];
    const float* attn_r = (const float*)d_in[3];
    const int*   src    = (const int*)d_in[4];
    const int*   dst    = (const int*)d_in[5];
    float* out = (float*)d_out;

    char* ws = (char*)d_ws;
    unsigned short* feat = (unsigned short*)ws;             // 76,800,000 B
    float* el4 = (float*)(ws + 76800000);                   // 200000*4*4 = 3,200,000 B
    float* er4 = (float*)(ws + 80000000);                   // 50000*4*4  =   800,000 B
    unsigned short* Wp = (unsigned short*)(ws + 80800000);  //     98,304 B
    int*   rp = (int*)(ws + 80898304);                      //    200,004 B

    prep_kernel<<<24 + 196, 256, 0, stream>>>(W, Wp, dst, rp);
    gemm_feat<<<NRB, 256, 0, stream>>>(x, Wp, attn_l, attn_r, feat, el4, er4);
    gather_kernel<<<12500, 256, 0, stream>>>(feat, el4, er4, src, rp, out);
}

// Round 8
// 177.399 us; speedup vs baseline: 1.0717x; 1.0717x over previous
//
#include <hip/hip_runtime.h>
#include <hip/hip_bf16.h>

#define N_SRCN 200000
#define N_DSTN 50000
#define NEDGE 800000
#define KIN 256
#define NF 192        // H*OUT = 3*64
#define SLOPE 0.2f
#define TILES 6250    // 32-row tiles
#define GBLK 512      // persistent blocks (2 per CU exactly)

typedef __attribute__((ext_vector_type(8))) short bf16x8;
typedef __attribute__((ext_vector_type(4))) float f32x4;

__device__ __forceinline__ unsigned short f2bf(float f) {
    union { float f; unsigned int u; } v; v.f = f;
    unsigned int u = v.u;
    return (unsigned short)((u + 0x7FFFu + ((u >> 16) & 1u)) >> 16);  // RNE
}
__device__ __forceinline__ float bf2f(unsigned short h) {
    union { unsigned int u; float f; } v; v.u = ((unsigned int)h) << 16;
    return v.f;
}
__device__ __forceinline__ unsigned int cvt2(float lo, float hi) {
    __hip_bfloat162 h = __float22bfloat162_rn(float2{lo, hi});
    union { __hip_bfloat162 h; unsigned int u; } c; c.h = h;
    return c.u;
}
__device__ __forceinline__ void gl_lds16(const void* g, void* l) {
    __builtin_amdgcn_global_load_lds(
        (const __attribute__((address_space(1))) unsigned int*)g,
        (__attribute__((address_space(3))) unsigned int*)l, 16, 0, 0);
}

// ---------------- merged prep: blocks 0-23 pack W; blocks 24+ build row_ptr --
__global__ void prep_kernel(const float* __restrict__ W, unsigned short* __restrict__ Wp,
                            const int* __restrict__ dst, int* __restrict__ rp) {
    const int bid = blockIdx.x;
    if (bid < 24) {
        int tid = bid * 256 + threadIdx.x;
        if (tid >= 12 * 8 * 64) return;
        int lane = tid & 63;
        int g = tid >> 6;
        int nt = g % 12, ks = g / 12;
        int col = nt * 16 + (lane & 15);
        int k = ks * 32 + (lane >> 4) * 8;
        const float* wsrc = &W[col * KIN + k];
        unsigned short* o = &Wp[tid * 8];
        #pragma unroll
        for (int j = 0; j < 8; ++j) o[j] = f2bf(wsrc[j]);
    } else {
        int d = (bid - 24) * 256 + threadIdx.x;
        if (d > N_DSTN) return;
        int lo = 0, hi = NEDGE;
        while (lo < hi) {
            int mid = (lo + hi) >> 1;
            if (dst[mid] < d) lo = mid + 1; else hi = mid;
        }
        rp[d] = lo;
    }
}

// ---------------- GEMM: feat = x @ W^T (bf16 MFMA) + fused el/er -------------
// Persistent 512 blocks (2/CU), 32-row tiles, B in regs ONCE (24 frags = 96
// VGPR; budget 256 via launch_bounds(256,2)). x DMA-double-buffered into LDS
// with counted vmcnt(8) — loads for tile t+1 in flight across tile t compute.
__launch_bounds__(256, 2)
__global__ void gemm_feat(const float* __restrict__ x, const unsigned short* __restrict__ Wp,
                          const float* __restrict__ attn_l, const float* __restrict__ attn_r,
                          unsigned short* __restrict__ feat,
                          float* __restrict__ el4, float* __restrict__ er4) {
    __shared__ float Ab[2][32][256];         // 64 KB f32 dbuf
    __shared__ float parts[32][4][4][2];     // 4 KB [row][head(pad4)][ntq][l/r]
    const int t = threadIdx.x;
    const int wid = t >> 6, lane = t & 63;
    const int al = lane & 15, ah = lane >> 4;

    // ---- B preload (once per block): wave w -> nt = 3w+j ----
    bf16x8 bv[8][3];
    #pragma unroll
    for (int ks = 0; ks < 8; ++ks)
        #pragma unroll
        for (int j = 0; j < 3; ++j)
            bv[ks][j] = *(const bf16x8*)&Wp[(size_t)(ks * 12 + wid * 3 + j) * 512 + lane * 8];

    float Al[3], Ar[3];
    #pragma unroll
    for (int j = 0; j < 3; ++j) {
        Al[j] = attn_l[(wid * 3 + j) * 16 + al];
        Ar[j] = attn_r[(wid * 3 + j) * 16 + al];
    }

    // ---- stage helper pattern: wave w stages rows [w*8, w*8+8); one row
    // (1 KB) per DMA call; source granule pre-swizzled: LDS slot q holds
    // logical granule q^(row&7)  (rule #21: swizzle source + read, LDS linear)
    #define STAGE(buf, tile)                                                     \
        {                                                                        \
            const int rbase = (tile) * 32;                                       \
            _Pragma("unroll")                                                    \
            for (int rr = 0; rr < 8; ++rr) {                                     \
                const int rl = wid * 8 + rr;                                     \
                const float* gp = &x[(size_t)(rbase + rl) * KIN +                \
                                     ((lane ^ (rl & 7)) << 2)];                  \
                gl_lds16(gp, &Ab[buf][rl][0]);                                   \
            }                                                                    \
        }

    // prologue: stage first tile
    STAGE(0, blockIdx.x)

    for (int tl = blockIdx.x, it = 0; tl < TILES; tl += GBLK, ++it) {
        const int cur = it & 1;
        if (tl + GBLK < TILES) {
            STAGE(cur ^ 1, tl + GBLK)
            asm volatile("s_waitcnt vmcnt(8)" ::: "memory");   // old 8 done, new 8 in flight
        } else {
            asm volatile("s_waitcnt vmcnt(0)" ::: "memory");
        }
        __syncthreads();

        const int r0 = tl * 32;
        f32x4 acc[2][3] = {};
        #pragma unroll
        for (int ks = 0; ks < 8; ++ks) {
            #pragma unroll
            for (int rt = 0; rt < 2; ++rt) {
                const int row = rt * 16 + al;
                const int q0 = (ks * 8 + ah * 2);
                const int key = row & 7;
                const float4 v0 = *(const float4*)&Ab[cur][row][((q0 ^ key) << 2)];
                const float4 v1 = *(const float4*)&Ab[cur][row][(((q0 + 1) ^ key) << 2)];
                union { bf16x8 v; unsigned int u[4]; } av;
                av.u[0] = cvt2(v0.x, v0.y);
                av.u[1] = cvt2(v0.z, v0.w);
                av.u[2] = cvt2(v1.x, v1.y);
                av.u[3] = cvt2(v1.z, v1.w);
                #pragma unroll
                for (int j = 0; j < 3; ++j)
                    acc[rt][j] = __builtin_amdgcn_mfma_f32_16x16x32_bf16(av.v, bv[ks][j], acc[rt][j], 0, 0, 0);
            }
        }

        // epilogue 1: feat store (C/D: col=nt*16+al, row=ah*4+e [m89])
        #pragma unroll
        for (int rt = 0; rt < 2; ++rt)
            #pragma unroll
            for (int j = 0; j < 3; ++j) {
                const int col = (wid * 3 + j) * 16 + al;
                #pragma unroll
                for (int e = 0; e < 4; ++e) {
                    const int row = r0 + rt * 16 + ah * 4 + e;
                    feat[(size_t)row * NF + col] = f2bf(acc[rt][j][e]);
                }
            }

        // epilogue 2: el/er partials (16-lane reduce per nt)
        #pragma unroll
        for (int rt = 0; rt < 2; ++rt)
            #pragma unroll
            for (int e = 0; e < 4; ++e)
                #pragma unroll
                for (int j = 0; j < 3; ++j) {
                    float sl = acc[rt][j][e] * Al[j];
                    float sr = acc[rt][j][e] * Ar[j];
                    #pragma unroll
                    for (int m = 1; m <= 8; m <<= 1) {
                        sl += __shfl_xor(sl, m);
                        sr += __shfl_xor(sr, m);
                    }
                    if (al == 0) {
                        const int rloc = rt * 16 + ah * 4 + e;
                        const int nt = wid * 3 + j;
                        parts[rloc][nt >> 2][nt & 3][0] = sl;
                        parts[rloc][nt >> 2][nt & 3][1] = sr;
                    }
                }
        __syncthreads();   // also protects Ab[cur] until all reads done

        if (t < 128) {
            const int rloc = t >> 2, h = t & 3;
            const int row = r0 + rloc;
            float sl = 0.f, sr = 0.f;
            if (h < 3) {
                sl = parts[rloc][h][0][0] + parts[rloc][h][1][0]
                   + parts[rloc][h][2][0] + parts[rloc][h][3][0];
                sr = parts[rloc][h][0][1] + parts[rloc][h][1][1]
                   + parts[rloc][h][2][1] + parts[rloc][h][3][1];
            }
            el4[(size_t)row * 4 + h] = sl;
            if (row < N_DSTN) er4[(size_t)row * 4 + h] = sr;
        }
        // parts re-written only after next __syncthreads() -> safe
    }
    #undef STAGE
}

// ---------------- gather: edge softmax (no max shift) + weighted accumulate --
__launch_bounds__(256)
__global__ void gather_kernel(const unsigned short* __restrict__ feat,
                              const float* __restrict__ el4, const float* __restrict__ er4,
                              const int* __restrict__ src, const int* __restrict__ rp,
                              float* __restrict__ out) {
    const int lane = threadIdx.x & 63;
    const int d = (blockIdx.x * blockDim.x + threadIdx.x) >> 6;
    if (d >= N_DSTN) return;
    const int lo = rp[d], hi = rp[d + 1];
    const float4 erv = *(const float4*)&er4[(size_t)d * 4];

    float a0 = 0.f, a1 = 0.f, a2 = 0.f, s0 = 0.f, s1 = 0.f, s2 = 0.f;
    for (int base = lo; base < hi; base += 64) {
        const int cnt = min(64, hi - base);
        int sv = 0; float w0 = 0.f, w1 = 0.f, w2 = 0.f;
        if (lane < cnt) {
            sv = src[base + lane];
            const float4 elv = *(const float4*)&el4[(size_t)sv * 4];
            float e0 = elv.x + erv.x; e0 = e0 >= 0.f ? e0 : SLOPE * e0; w0 = __expf(e0);
            float e1 = elv.y + erv.y; e1 = e1 >= 0.f ? e1 : SLOPE * e1; w1 = __expf(e1);
            float e2 = elv.z + erv.z; e2 = e2 >= 0.f ? e2 : SLOPE * e2; w2 = __expf(e2);
        }
        int j = 0;
        for (; j + 8 <= cnt; j += 8) {
            unsigned short f0[8], f1[8], f2[8];
            float u0[8], u1[8], u2[8];
            #pragma unroll
            for (int q = 0; q < 8; ++q) {
                const int sj = __shfl(sv, j + q);
                const unsigned short* fp = &feat[(size_t)sj * NF + lane];
                f0[q] = fp[0]; f1[q] = fp[64]; f2[q] = fp[128];
                u0[q] = __shfl(w0, j + q);
                u1[q] = __shfl(w1, j + q);
                u2[q] = __shfl(w2, j + q);
            }
            #pragma unroll
            for (int q = 0; q < 8; ++q) {
                s0 += u0[q]; a0 += u0[q] * bf2f(f0[q]);
                s1 += u1[q]; a1 += u1[q] * bf2f(f1[q]);
                s2 += u2[q]; a2 += u2[q] * bf2f(f2[q]);
            }
        }
        for (; j < cnt; ++j) {
            const int sj = __shfl(sv, j);
            const float u0 = __shfl(w0, j);
            const float u1 = __shfl(w1, j);
            const float u2 = __shfl(w2, j);
            const unsigned short* fp = &feat[(size_t)sj * NF + lane];
            s0 += u0; a0 += u0 * bf2f(fp[0]);
            s1 += u1; a1 += u1 * bf2f(fp[64]);
            s2 += u2; a2 += u2 * bf2f(fp[128]);
        }
    }
    if (hi == lo) { s0 = 1.f; s1 = 1.f; s2 = 1.f; }
    float* op = &out[(size_t)d * NF];
    op[lane]       = a0 / s0;
    op[64 + lane]  = a1 / s1;
    op[128 + lane] = a2 / s2;
}

extern "C" void kernel_launch(void* const* d_in, const int* in_sizes, int n_in,
                              void* d_out, int out_size, void* d_ws, size_t ws_size,
                              hipStream_t stream) {
    const float* x      = (const float*)d_in[0];
    const float* W      = (const float*)d_in[1];
    const float* attn_l = (const float*)d_in[2];
    const float* attn_r = (const float*)d_in[3];
    const int*   src    = (const int*)d_in[4];
    const int*   dst    = (const int*)d_in[5];
    float* out = (float*)d_out;

    char* ws = (char*)d_ws;
    unsigned short* feat = (unsigned short*)ws;             // 76,800,000 B
    float* el4 = (float*)(ws + 76800000);                   // 3,200,000 B
    float* er4 = (float*)(ws + 80000000);                   //   800,000 B
    unsigned short* Wp = (unsigned short*)(ws + 80800000);  //    98,304 B
    int*   rp = (int*)(ws + 80898304);                      //   200,004 B

    prep_kernel<<<24 + 196, 256, 0, stream>>>(W, Wp, dst, rp);
    gemm_feat<<<GBLK, 256, 0, stream>>>(x, Wp, attn_l, attn_r, feat, el4, er4);
    gather_kernel<<<12500, 256, 0, stream>>>(feat, el4, er4, src, rp, out);
}